// Round 2
// baseline (6689.190 us; speedup 1.0000x reference)
//
#include <hip/hip_runtime.h>
#include <hip/hip_fp16.h>
#include <hip/hip_cooperative_groups.h>

namespace cg = cooperative_groups;

#define HW   1600
#define NP1  1601
#define NPAD 1608          // padded row length (elements), %8==0
#define NC   256
#define NB   8
#define MU_  (1.0f/3200.0f)
#define ITERS 24           // contraction ~0.23/iter -> 1e-15 truncation, == 100-iter fixed point
#define GBLK 1024          // cooperative grid (4 blocks/CU on 256 CUs)
#define BPB  128           // blocks per batch (GBLK/NB); bid%8 == batch == XCD
#define RPB  13            // rows per block (ceil(1601/128))

// ---------- transpose A planes: fa[b][c][m] = A[b][c][m%40][m/40] ----------
__global__ void k_transpose(const float* __restrict__ A, float* __restrict__ fa) {
  __shared__ float lds[HW];
  int plane = blockIdx.x;
  const float* src = A + (size_t)plane * HW;
  float* dst = fa + (size_t)plane * HW;
  for (int p = threadIdx.x; p < HW; p += 256) lds[p] = src[p];
  __syncthreads();
  for (int q = threadIdx.x; q < HW; q += 256) dst[q] = lds[(q % 40) * 40 + q / 40];
}

// ---------- init: colsq=0, cd[buf0]=nu (b=1; pads->1), nuvec, ot=0 ----------
__global__ void k_init(float* colsq, float* cd, float* nuvec, float* ot) {
  int idx = blockIdx.x * 256 + threadIdx.x;
  if (idx < NB * HW) colsq[idx] = 0.f;
  if (idx < NPAD) nuvec[idx] = (idx < HW) ? MU_ : (idx == HW ? 0.5f : 0.f);
  if (idx < NB * NPAD) {
    int j = idx % NPAD;
    cd[idx] = (j < HW) ? MU_ : (j == HW ? 0.5f : 1.0f);
  }
  if (idx < NB) ot[idx] = 0.f;
}

// ---------- GEMM: corr(fp16) = relu(fa^T fb), colsq += corr^2 ----------
#define BM 128
#define BN 128
#define BK 16
#define SW(j) ((j) + (((j) >> 5) << 2))   // 2-way (free) LDS bank pattern for B reads

__global__ __launch_bounds__(256) void k_gemm(const float* __restrict__ fa,
                                              const float* __restrict__ fb,
                                              float* __restrict__ colsq,
                                              __half* __restrict__ corr) {
  __shared__ float As[BK][BM];
  __shared__ float Bs[BK][144];
  __shared__ float cs[BN];

  int b  = blockIdx.z;
  int m0 = blockIdx.y * BM;
  int n0 = blockIdx.x * BN;
  int tid = threadIdx.x;
  int tx = tid & 15, ty = tid >> 4;

  float acc[8][8];
#pragma unroll
  for (int r = 0; r < 8; ++r)
#pragma unroll
    for (int c = 0; c < 8; ++c) acc[r][c] = 0.f;

  const float* fab = fa + (size_t)b * NC * HW;
  const float* fbb = fb + (size_t)b * NC * HW;

  for (int k0 = 0; k0 < NC; k0 += BK) {
#pragma unroll
    for (int l = 0; l < 2; ++l) {
      int id = tid + l * 256;
      int kk = id >> 5, mq = id & 31;
      int m = m0 + mq * 4;
      float4 v = make_float4(0.f, 0.f, 0.f, 0.f);
      if (m < HW) v = *(const float4*)(fab + (size_t)(k0 + kk) * HW + m);
      *(float4*)&As[kk][mq * 4] = v;
      int n = n0 + mq * 4;
      float4 w = make_float4(0.f, 0.f, 0.f, 0.f);
      if (n < HW) w = *(const float4*)(fbb + (size_t)(k0 + kk) * HW + n);
      *(float4*)&Bs[kk][SW(mq * 4)] = w;
    }
    __syncthreads();
#pragma unroll
    for (int kk = 0; kk < BK; ++kk) {
      float a[8], bb[8];
      *(float4*)&a[0]  = *(float4*)&As[kk][ty * 8];
      *(float4*)&a[4]  = *(float4*)&As[kk][ty * 8 + 4];
      *(float4*)&bb[0] = *(float4*)&Bs[kk][SW(tx * 8)];
      *(float4*)&bb[4] = *(float4*)&Bs[kk][SW(tx * 8) + 4];
#pragma unroll
      for (int r = 0; r < 8; ++r)
#pragma unroll
        for (int c = 0; c < 8; ++c) acc[r][c] = fmaf(a[r], bb[c], acc[r][c]);
    }
    __syncthreads();
  }

  if (tid < BN) cs[tid] = 0.f;
  __syncthreads();

  float csum[8];
#pragma unroll
  for (int c = 0; c < 8; ++c) csum[c] = 0.f;
#pragma unroll
  for (int r = 0; r < 8; ++r) {
    int m = m0 + ty * 8 + r;
    __half hv[8];
#pragma unroll
    for (int c = 0; c < 8; ++c) {
      float x = fmaxf(acc[r][c], 0.f);
      hv[c] = __float2half(x);
      csum[c] += x * x;
    }
    if (m < HW && (n0 + tx * 8) < HW)
      *(uint4*)(corr + (size_t)(b * NP1 + m) * NPAD + n0 + tx * 8) = *(uint4*)hv;
  }
#pragma unroll
  for (int c = 0; c < 8; ++c) atomicAdd(&cs[tx * 8 + c], csum[c]);
  __syncthreads();
  if (tid < BN) {
    int n = n0 + tid;
    if (n < HW) atomicAdd(&colsq[b * HW + n], cs[tid]);
  }
}

// ---------- normalize + exp: khat = exp(corr / (sqrt(colsq+eps)*16)) ----------
__global__ void k_normexp(const __half* __restrict__ corr,
                          const float* __restrict__ colsq,
                          __half* __restrict__ khat) {
  int idx = blockIdx.x * 256 + threadIdx.x;     // NB*HW*200 chunks of 8 cols
  if (idx >= NB * HW * 200) return;
  int c = idx % 200;
  int rem = idx / 200;
  int m = rem % HW, b = rem / HW;
  const __half* cp = corr + (size_t)(b * NP1 + m) * NPAD + c * 8;
  uint4 kk = *(const uint4*)cp;
  float4 q0 = *(const float4*)(colsq + (size_t)b * HW + c * 8);
  float4 q1 = *(const float4*)(colsq + (size_t)b * HW + c * 8 + 4);
  __half2 h0 = *(__half2*)&kk.x, h1 = *(__half2*)&kk.y;
  __half2 h2 = *(__half2*)&kk.z, h3 = *(__half2*)&kk.w;
  float v[8] = {__low2float(h0), __high2float(h0), __low2float(h1), __high2float(h1),
                __low2float(h2), __high2float(h2), __low2float(h3), __high2float(h3)};
  float q[8] = {q0.x, q0.y, q0.z, q0.w, q1.x, q1.y, q1.z, q1.w};
  __half hv[8];
#pragma unroll
  for (int i = 0; i < 8; ++i) {
    float inv = 1.0f / (sqrtf(q[i] + 1e-6f) * 16.0f);
    hv[i] = __float2half(__expf(v[i] * inv));
  }
  *(uint4*)(khat + (size_t)(b * NP1 + m) * NPAD + c * 8) = *(uint4*)hv;
}

// ---------- bin row/col fill ----------
__global__ void k_fill(__half* khat, const float* alpha) {
  float E = expf(alpha[0]);
  __half he = __float2half(E);
  __half hz = __float2half(0.f);
  int t = blockIdx.x * 256 + threadIdx.x;
  if (t >= NB * NP1) return;
  int i = t % NP1;
  __half* row = khat + (size_t)t * NPAD;
  if (i < HW) {
    __half hv[8] = {he, hz, hz, hz, hz, hz, hz, hz};
    *(uint4*)(row + HW) = *(uint4*)hv;          // cols 1600..1607
  } else {
    for (int j = 0; j < NPAD; j += 8) {
      __half hv[8];
      for (int k = 0; k < 8; ++k) hv[k] = ((j + k) <= HW) ? he : hz;
      *(uint4*)(row + j) = *(uint4*)hv;
    }
  }
}

// ---------- persistent cooperative Sinkhorn + OT epilogue ----------
// b_j is implicit: b = nu/cd, cd = column sums of K*a.  2 grid syncs / iter.
__global__ __launch_bounds__(256, 4) void k_sinkhorn(
    const __half* __restrict__ khat, const float* __restrict__ nuvec,
    float* __restrict__ cd, float* __restrict__ ot, float* __restrict__ out) {
  cg::grid_group grid = cg::this_grid();
  __shared__ float binv[NPAD];
  __shared__ float a_lds[RPB];

  int bid = blockIdx.x;
  int bb = bid & 7;                 // batch == XCD (default round-robin)
  int lb = bid >> 3;                // 0..127 within batch
  int r0 = lb * RPB;
  int r1 = min(r0 + RPB, NP1);
  int z1 = min(r0 + RPB, NPAD);     // zeroing slice over NPAD
  int tid = threadIdx.x, wid = tid >> 6, lane = tid & 63;

  const __half* Kb = khat + (size_t)bb * NP1 * NPAD;
  float* cd0 = cd + (size_t)bb * NPAD;
  float* cd1 = cd + (size_t)(NB + bb) * NPAD;

  for (int t = 0; t < ITERS; ++t) {
    float* cdr = (t & 1) ? cd1 : cd0;
    float* cdw = (t & 1) ? cd0 : cd1;
    for (int j = tid; j < NPAD; j += 256) binv[j] = nuvec[j] / cdr[j];
    for (int j = r0 + tid; j < z1; j += 256) cdw[j] = (j <= HW) ? 0.f : 1.f;
    __syncthreads();
    // Phase A: a_i = mu_i / sum_j K[i][j] b_j   (wave per row)
    for (int r = r0 + wid; r < r1; r += 4) {
      const __half* kr = Kb + (size_t)r * NPAD;
      float acc = 0.f;
      for (int c = lane; c < NPAD / 8; c += 64) {
        uint4 kk = *(const uint4*)(kr + c * 8);
        float4 b0 = *(const float4*)&binv[c * 8];
        float4 b1 = *(const float4*)&binv[c * 8 + 4];
        __half2 h0 = *(__half2*)&kk.x, h1 = *(__half2*)&kk.y;
        __half2 h2 = *(__half2*)&kk.z, h3 = *(__half2*)&kk.w;
        acc = fmaf(__low2float(h0),  b0.x, acc);
        acc = fmaf(__high2float(h0), b0.y, acc);
        acc = fmaf(__low2float(h1),  b0.z, acc);
        acc = fmaf(__high2float(h1), b0.w, acc);
        acc = fmaf(__low2float(h2),  b1.x, acc);
        acc = fmaf(__high2float(h2), b1.y, acc);
        acc = fmaf(__low2float(h3),  b1.z, acc);
        acc = fmaf(__high2float(h3), b1.w, acc);
      }
#pragma unroll
      for (int o = 32; o > 0; o >>= 1) acc += __shfl_xor(acc, o, 64);
      if (lane == 0) {
        float mu = (r < HW) ? MU_ : 0.5f;
        a_lds[r - r0] = mu / acc;
      }
    }
    __syncthreads();
    grid.sync();
    // Phase B: cdw[j] += sum_{my rows} K[r][j] * a_r   (thread owns 8 cols)
    if (tid < NPAD / 8) {
      int j0 = tid * 8;
      float ca[8];
#pragma unroll
      for (int i = 0; i < 8; ++i) ca[i] = 0.f;
      for (int r = r0; r < r1; ++r) {
        float aa = a_lds[r - r0];
        uint4 kk = *(const uint4*)(Kb + (size_t)r * NPAD + j0);
        __half2 h0 = *(__half2*)&kk.x, h1 = *(__half2*)&kk.y;
        __half2 h2 = *(__half2*)&kk.z, h3 = *(__half2*)&kk.w;
        ca[0] = fmaf(__low2float(h0),  aa, ca[0]);
        ca[1] = fmaf(__high2float(h0), aa, ca[1]);
        ca[2] = fmaf(__low2float(h1),  aa, ca[2]);
        ca[3] = fmaf(__high2float(h1), aa, ca[3]);
        ca[4] = fmaf(__low2float(h2),  aa, ca[4]);
        ca[5] = fmaf(__high2float(h2), aa, ca[5]);
        ca[6] = fmaf(__low2float(h3),  aa, ca[6]);
        ca[7] = fmaf(__high2float(h3), aa, ca[7]);
      }
#pragma unroll
      for (int i = 0; i < 8; ++i) atomicAdd(&cdw[j0 + i], ca[i]);
    }
    grid.sync();
  }

  // Epilogue: ot[bb] += a_i * sum_{j<1600} K ln(K) b_j  (interior only)
  {
    float* cdf = (ITERS & 1) ? cd1 : cd0;
    for (int j = tid; j < NPAD; j += 256) binv[j] = nuvec[j] / cdf[j];
    __syncthreads();
    for (int r = r0 + wid; r < r1; r += 4) {
      if (r >= HW) continue;
      const __half* kr = Kb + (size_t)r * NPAD;
      float acc = 0.f;
      for (int c = lane; c < HW / 8; c += 64) {
        uint4 kk = *(const uint4*)(kr + c * 8);
        float4 b0 = *(const float4*)&binv[c * 8];
        float4 b1 = *(const float4*)&binv[c * 8 + 4];
        __half2 h0 = *(__half2*)&kk.x, h1 = *(__half2*)&kk.y;
        __half2 h2 = *(__half2*)&kk.z, h3 = *(__half2*)&kk.w;
        float f;
        f = __low2float(h0);  acc = fmaf(f * __logf(f), b0.x, acc);
        f = __high2float(h0); acc = fmaf(f * __logf(f), b0.y, acc);
        f = __low2float(h1);  acc = fmaf(f * __logf(f), b0.z, acc);
        f = __high2float(h1); acc = fmaf(f * __logf(f), b0.w, acc);
        f = __low2float(h2);  acc = fmaf(f * __logf(f), b1.x, acc);
        f = __high2float(h2); acc = fmaf(f * __logf(f), b1.y, acc);
        f = __low2float(h3);  acc = fmaf(f * __logf(f), b1.z, acc);
        f = __high2float(h3); acc = fmaf(f * __logf(f), b1.w, acc);
      }
#pragma unroll
      for (int o = 32; o > 0; o >>= 1) acc += __shfl_xor(acc, o, 64);
      if (lane == 0) atomicAdd(&ot[bb], a_lds[r - r0] * acc);
    }
    grid.sync();
    if (bid == 0 && tid < NB) out[tid] = __expf(-3200.f * ot[tid]);
  }
}

extern "C" void kernel_launch(void* const* d_in, const int* in_sizes, int n_in,
                              void* d_out, int out_size, void* d_ws, size_t ws_size,
                              hipStream_t stream) {
  const float* A     = (const float*)d_in[0];
  const float* Bf    = (const float*)d_in[1];
  const float* alpha = (const float*)d_in[2];
  float* out = (float*)d_out;

  char* ws = (char*)d_ws;
  size_t off = 0;
  auto alloc = [&](size_t bytes) -> void* {
    void* p = (void*)(ws + off);
    off += (bytes + 255) & ~(size_t)255;
    return p;
  };
  float*  fa    = (float*)alloc((size_t)NB * NC * HW * 4);        // 13.1 MB
  __half* corr  = (__half*)alloc((size_t)NB * NP1 * NPAD * 2);    // 41.2 MB
  __half* khat  = (__half*)alloc((size_t)NB * NP1 * NPAD * 2);    // 41.2 MB
  float*  colsq = (float*)alloc((size_t)NB * HW * 4);
  float*  cd    = (float*)alloc((size_t)2 * NB * NPAD * 4);
  float*  nuvec = (float*)alloc((size_t)NPAD * 4);
  float*  ot    = (float*)alloc((size_t)NB * 4);

  hipLaunchKernelGGL(k_init, dim3((NB * NPAD + 255) / 256), dim3(256), 0, stream,
                     colsq, cd, nuvec, ot);
  hipLaunchKernelGGL(k_transpose, dim3(NB * NC), dim3(256), 0, stream, A, fa);

  dim3 gg((HW + BN - 1) / BN, (HW + BM - 1) / BM, NB);
  hipLaunchKernelGGL(k_gemm, gg, dim3(256), 0, stream, fa, Bf, colsq, corr);
  hipLaunchKernelGGL(k_normexp, dim3((NB * HW * 200 + 255) / 256), dim3(256), 0, stream,
                     corr, colsq, khat);
  hipLaunchKernelGGL(k_fill, dim3((NB * NP1 + 255) / 256), dim3(256), 0, stream,
                     khat, alpha);

  void* args[] = { (void*)&khat, (void*)&nuvec, (void*)&cd, (void*)&ot, (void*)&out };
  hipLaunchCooperativeKernel((const void*)k_sinkhorn, dim3(GBLK), dim3(256),
                             args, 0, stream);
}

// Round 3
// 503.806 us; speedup vs baseline: 13.2773x; 13.2773x over previous
//
#include <hip/hip_runtime.h>
#include <hip/hip_fp16.h>

#define HW   1600
#define NP1  1601
#define NPAD 1608          // padded row length (elements), %8==0
#define NC   256
#define NB   8
#define MROW 1664          // GEMM row padding (13*128)
#define MU_  (1.0f/3200.0f)
#define ITERS 12           // contraction ~0.21/iter -> ~1e-8 rel truncation

typedef _Float16 half8 __attribute__((ext_vector_type(8)));
typedef float    floatx4 __attribute__((ext_vector_type(4)));

// ---------- permute A planes: fa32[b][c][m] = A[b][c][m%40][m/40] ----------
__global__ void k_permA(const float* __restrict__ A, float* __restrict__ fa32) {
  __shared__ float lds[HW];
  int plane = blockIdx.x;
  const float* src = A + (size_t)plane * HW;
  float* dst = fa32 + (size_t)plane * HW;
  for (int p = threadIdx.x; p < HW; p += 256) lds[p] = src[p];
  __syncthreads();
  for (int q = threadIdx.x; q < HW; q += 256) dst[q] = lds[(q % 40) * 40 + q / 40];
}

// ---------- init ----------
__global__ void k_init(float* colsq, float* avec, float* bvec, float* ot) {
  int idx = blockIdx.x * 256 + threadIdx.x;
  if (idx < NB * HW) colsq[idx] = 0.f;
  if (idx < NB * NPAD) {
    int j = idx % NPAD;
    bvec[idx] = (j <= HW) ? 1.0f : 0.0f;
    avec[idx] = 0.0f;
  }
  if (idx < NB) ot[idx] = 0.f;
}

// ---------- tile transpose + fp32->fp16: out[b][m][c] = in[b][c][m] ----------
// in: [NB][NC][HW] fp32; out: [NB][MROW][NC] fp16, rows >= HW zeroed.
__global__ __launch_bounds__(256) void k_t2(const float* __restrict__ in,
                                            _Float16* __restrict__ out) {
  __shared__ float t[64][65];
  int b  = blockIdx.z;
  int c0 = blockIdx.y * 64;         // 4 tiles over NC
  int m0 = blockIdx.x * 64;         // 26 tiles over MROW (1600 % 64 == 0)
  int tid = threadIdx.x;
  int r = tid >> 3, jc = (tid & 7) * 8;
  const float* src = in + (size_t)b * NC * HW;
#pragma unroll
  for (int p = 0; p < 2; ++p) {
    int rr = r + p * 32;
    int c = c0 + rr;
    float4 v0 = make_float4(0.f, 0.f, 0.f, 0.f), v1 = v0;
    if (m0 < HW) {
      v0 = *(const float4*)(src + (size_t)c * HW + m0 + jc);
      v1 = *(const float4*)(src + (size_t)c * HW + m0 + jc + 4);
    }
    *(float4*)&t[rr][jc] = v0;
    *(float4*)&t[rr][jc + 4] = v1;
  }
  __syncthreads();
  _Float16* dst = out + (size_t)b * MROW * NC;
#pragma unroll
  for (int p = 0; p < 2; ++p) {
    int r2 = r + p * 32;
    int m = m0 + r2;
    _Float16 hv[8];
#pragma unroll
    for (int e = 0; e < 8; ++e) hv[e] = (_Float16)t[jc + e][r2];
    *(uint4*)(dst + (size_t)m * NC + c0 + jc) = *(uint4*)hv;
  }
}

// ---------- MFMA GEMM: corr(fp16) = relu(fa_mh . fb_nh^T), colsq += corr^2 ----
__global__ __launch_bounds__(256) void k_gemm(const _Float16* __restrict__ fa,
                                              const _Float16* __restrict__ fb,
                                              float* __restrict__ colsq,
                                              __half* __restrict__ corr) {
  __shared__ _Float16 As[128][40];   // 80B row stride: 16B-aligned, conflict-free frags
  __shared__ _Float16 Bs[128][40];
  __shared__ float cs[128];

  int b  = blockIdx.z;
  int m0 = blockIdx.y * 128;
  int n0 = blockIdx.x * 128;
  int tid = threadIdx.x, lane = tid & 63, w = tid >> 6;
  int wr = w >> 1, wc = w & 1;       // 2x2 waves, each 64x64
  const _Float16* Ab = fa + (size_t)b * MROW * NC;
  const _Float16* Bb = fb + (size_t)b * MROW * NC;

  floatx4 acc[4][4];
#pragma unroll
  for (int i = 0; i < 4; ++i)
#pragma unroll
    for (int j = 0; j < 4; ++j) acc[i][j] = (floatx4){0.f, 0.f, 0.f, 0.f};

  for (int k0 = 0; k0 < NC; k0 += 32) {
#pragma unroll
    for (int l = 0; l < 2; ++l) {
      int id = tid + l * 256;                    // 0..511
      int row = id >> 2, ch = id & 3;
      *(uint4*)&As[row][ch * 8] = *(const uint4*)(Ab + (size_t)(m0 + row) * NC + k0 + ch * 8);
      *(uint4*)&Bs[row][ch * 8] = *(const uint4*)(Bb + (size_t)(n0 + row) * NC + k0 + ch * 8);
    }
    __syncthreads();
    half8 af[4], bf[4];
#pragma unroll
    for (int i = 0; i < 4; ++i)
      af[i] = *(half8*)&As[wr * 64 + i * 16 + (lane & 15)][(lane >> 4) * 8];
#pragma unroll
    for (int j = 0; j < 4; ++j)
      bf[j] = *(half8*)&Bs[wc * 64 + j * 16 + (lane & 15)][(lane >> 4) * 8];
#pragma unroll
    for (int i = 0; i < 4; ++i)
#pragma unroll
      for (int j = 0; j < 4; ++j)
        acc[i][j] = __builtin_amdgcn_mfma_f32_16x16x32_f16(af[i], bf[j], acc[i][j], 0, 0, 0);
    __syncthreads();
  }

  if (tid < 128) cs[tid] = 0.f;
  __syncthreads();

#pragma unroll
  for (int j = 0; j < 4; ++j) {
    int n = n0 + wc * 64 + j * 16 + (lane & 15);
    float s = 0.f;
#pragma unroll
    for (int i = 0; i < 4; ++i) {
      int mb = m0 + wr * 64 + i * 16 + (lane >> 4) * 4;
#pragma unroll
      for (int e = 0; e < 4; ++e) {
        float x = fmaxf(acc[i][j][e], 0.f);
        s += x * x;
        int m = mb + e;
        if (m < HW && n < HW)
          corr[(size_t)(b * NP1 + m) * NPAD + n] = __float2half(x);
      }
    }
    s += __shfl_xor(s, 16, 64);
    s += __shfl_xor(s, 32, 64);
    if (lane < 16) atomicAdd(&cs[wc * 64 + j * 16 + lane], s);
  }
  __syncthreads();
  if (tid < 128) {
    int n = n0 + tid;
    if (n < HW) atomicAdd(&colsq[b * HW + n], cs[tid]);
  }
}

// ---------- normalize + exp: khat = exp(corr / (sqrt(colsq+eps)*16)) ----------
__global__ void k_normexp(const __half* __restrict__ corr,
                          const float* __restrict__ colsq,
                          __half* __restrict__ khat) {
  int idx = blockIdx.x * 256 + threadIdx.x;
  if (idx >= NB * HW * 200) return;
  int c = idx % 200;
  int rem = idx / 200;
  int m = rem % HW, b = rem / HW;
  uint4 kk = *(const uint4*)(corr + (size_t)(b * NP1 + m) * NPAD + c * 8);
  float4 q0 = *(const float4*)(colsq + (size_t)b * HW + c * 8);
  float4 q1 = *(const float4*)(colsq + (size_t)b * HW + c * 8 + 4);
  __half2 h0 = *(__half2*)&kk.x, h1 = *(__half2*)&kk.y;
  __half2 h2 = *(__half2*)&kk.z, h3 = *(__half2*)&kk.w;
  float v[8] = {__low2float(h0), __high2float(h0), __low2float(h1), __high2float(h1),
                __low2float(h2), __high2float(h2), __low2float(h3), __high2float(h3)};
  float q[8] = {q0.x, q0.y, q0.z, q0.w, q1.x, q1.y, q1.z, q1.w};
  __half hv[8];
#pragma unroll
  for (int i = 0; i < 8; ++i) {
    float inv = 1.0f / (sqrtf(q[i] + 1e-6f) * 16.0f);
    hv[i] = __float2half(__expf(v[i] * inv));
  }
  *(uint4*)(khat + (size_t)(b * NP1 + m) * NPAD + c * 8) = *(uint4*)hv;
}

// ---------- bin row/col fill ----------
__global__ void k_fill(__half* khat, const float* alpha) {
  float E = expf(alpha[0]);
  __half he = __float2half(E);
  __half hz = __float2half(0.f);
  int t = blockIdx.x * 256 + threadIdx.x;
  if (t >= NB * NP1) return;
  int i = t % NP1;
  __half* row = khat + (size_t)t * NPAD;
  if (i < HW) {
    __half hv[8] = {he, hz, hz, hz, hz, hz, hz, hz};
    *(uint4*)(row + HW) = *(uint4*)hv;
  } else {
    for (int j = 0; j < NPAD; j += 8) {
      __half hv[8];
      for (int k = 0; k < 8; ++k) hv[k] = ((j + k) <= HW) ? he : hz;
      *(uint4*)(row + j) = *(uint4*)hv;
    }
  }
}

// ---------- fp16 tiled transpose: khatT[b][j][i] = khat[b][i][j] ----------
__global__ __launch_bounds__(256) void k_tr(const __half* __restrict__ kh,
                                            __half* __restrict__ kt) {
  __shared__ __half t[64][72];
  int b  = blockIdx.z;
  int j0 = blockIdx.y * 64;
  int i0 = blockIdx.x * 64;
  int tid = threadIdx.x;
  int r = tid >> 3, jc = (tid & 7) * 8;
  const __half* src = kh + (size_t)b * NP1 * NPAD;
  __half* dst = kt + (size_t)b * NP1 * NPAD;
#pragma unroll
  for (int p = 0; p < 2; ++p) {
    int rr = r + p * 32;
    int i = i0 + rr;
    uint4 v = make_uint4(0, 0, 0, 0);
    if (i < NP1 && (j0 + jc) < NPAD)
      v = *(const uint4*)(src + (size_t)i * NPAD + j0 + jc);
    *(uint4*)&t[rr][jc] = v;
  }
  __syncthreads();
#pragma unroll
  for (int p = 0; p < 2; ++p) {
    int r2 = r + p * 32;
    int j = j0 + r2;
    if (j >= NP1 || (i0 + jc) >= NPAD) continue;
    __half hv[8];
#pragma unroll
    for (int e = 0; e < 8; ++e) hv[e] = t[jc + e][r2];
    *(uint4*)(dst + (size_t)j * NPAD + i0 + jc) = *(uint4*)hv;
  }
}

// ---------- Sinkhorn half-iteration: vout = mu / (K vin), wave per row ----------
__global__ __launch_bounds__(256) void k_sink(const __half* __restrict__ K,
                                              const float* __restrict__ vin,
                                              float* __restrict__ vout) {
  int wid = threadIdx.x >> 6;
  int lane = threadIdx.x & 63;
  int row = blockIdx.x * 4 + wid;
  if (row >= NB * NP1) return;
  int b = row / NP1, i = row % NP1;
  const __half* kr = K + (size_t)row * NPAD;
  const float* v = vin + (size_t)b * NPAD;
  float acc = 0.f;
  for (int c = lane; c < NPAD / 8; c += 64) {
    uint4 kk = *(const uint4*)(kr + c * 8);
    float4 v0 = *(const float4*)(v + c * 8);
    float4 v1 = *(const float4*)(v + c * 8 + 4);
    __half2 h0 = *(__half2*)&kk.x, h1 = *(__half2*)&kk.y;
    __half2 h2 = *(__half2*)&kk.z, h3 = *(__half2*)&kk.w;
    acc = fmaf(__low2float(h0),  v0.x, acc);
    acc = fmaf(__high2float(h0), v0.y, acc);
    acc = fmaf(__low2float(h1),  v0.z, acc);
    acc = fmaf(__high2float(h1), v0.w, acc);
    acc = fmaf(__low2float(h2),  v1.x, acc);
    acc = fmaf(__high2float(h2), v1.y, acc);
    acc = fmaf(__low2float(h3),  v1.z, acc);
    acc = fmaf(__high2float(h3), v1.w, acc);
  }
#pragma unroll
  for (int o = 32; o > 0; o >>= 1) acc += __shfl_xor(acc, o, 64);
  float mu = (i < HW) ? MU_ : 0.5f;
  if (lane == 0) vout[(size_t)b * NPAD + i] = mu / acc;
}

// ---------- Epilogue: ot[b] = sum_{i,j<1600} a_i b_j K ln(K) ----------
__global__ __launch_bounds__(256) void k_ot(const __half* __restrict__ khat,
                                            const float* __restrict__ avec,
                                            const float* __restrict__ bvec,
                                            float* __restrict__ ot) {
  int wid = threadIdx.x >> 6;
  int lane = threadIdx.x & 63;
  int row = blockIdx.x * 4 + wid;
  if (row >= NB * HW) return;
  int b = row / HW, i = row % HW;
  const __half* kr = khat + (size_t)(b * NP1 + i) * NPAD;
  const float* bv = bvec + (size_t)b * NPAD;
  float acc = 0.f;
  for (int c = lane; c < HW / 8; c += 64) {
    uint4 kk = *(const uint4*)(kr + c * 8);
    float4 v0 = *(const float4*)(bv + c * 8);
    float4 v1 = *(const float4*)(bv + c * 8 + 4);
    __half2 h0 = *(__half2*)&kk.x, h1 = *(__half2*)&kk.y;
    __half2 h2 = *(__half2*)&kk.z, h3 = *(__half2*)&kk.w;
    float f;
    f = __low2float(h0);  acc = fmaf(f * __logf(f), v0.x, acc);
    f = __high2float(h0); acc = fmaf(f * __logf(f), v0.y, acc);
    f = __low2float(h1);  acc = fmaf(f * __logf(f), v0.z, acc);
    f = __high2float(h1); acc = fmaf(f * __logf(f), v0.w, acc);
    f = __low2float(h2);  acc = fmaf(f * __logf(f), v1.x, acc);
    f = __high2float(h2); acc = fmaf(f * __logf(f), v1.y, acc);
    f = __low2float(h3);  acc = fmaf(f * __logf(f), v1.z, acc);
    f = __high2float(h3); acc = fmaf(f * __logf(f), v1.w, acc);
  }
#pragma unroll
  for (int o = 32; o > 0; o >>= 1) acc += __shfl_xor(acc, o, 64);
  if (lane == 0) atomicAdd(&ot[b], acc * avec[(size_t)b * NPAD + i]);
}

__global__ void k_final(const float* __restrict__ ot, float* __restrict__ out) {
  int b = threadIdx.x;
  if (b < NB) out[b] = expf(-3200.0f * ot[b]);
}

extern "C" void kernel_launch(void* const* d_in, const int* in_sizes, int n_in,
                              void* d_out, int out_size, void* d_ws, size_t ws_size,
                              hipStream_t stream) {
  const float* A     = (const float*)d_in[0];
  const float* Bf    = (const float*)d_in[1];
  const float* alpha = (const float*)d_in[2];
  float* out = (float*)d_out;

  char* ws = (char*)d_ws;
  size_t off = 0;
  auto alloc = [&](size_t bytes) -> void* {
    void* p = (void*)(ws + off);
    off += (bytes + 255) & ~(size_t)255;
    return p;
  };
  float*    fa32  = (float*)alloc((size_t)NB * NC * HW * 4);        // 13.1 MB (reused as fb_nh)
  _Float16* fa_mh = (_Float16*)alloc((size_t)NB * MROW * NC * 2);   // 6.8 MB
  __half*   corr  = (__half*)alloc((size_t)NB * NP1 * NPAD * 2);    // 41.2 MB (reused as khatT)
  __half*   khat  = (__half*)alloc((size_t)NB * NP1 * NPAD * 2);    // 41.2 MB
  float*    colsq = (float*)alloc((size_t)NB * HW * 4);
  float*    avec  = (float*)alloc((size_t)NB * NPAD * 4);
  float*    bvec  = (float*)alloc((size_t)NB * NPAD * 4);
  float*    ot    = (float*)alloc((size_t)NB * 4);

  _Float16* fb_nh = (_Float16*)fa32;   // alias: fa32 dead after k_t2(A)
  __half*   khatT = corr;              // alias: corr dead after k_normexp

  hipLaunchKernelGGL(k_init, dim3((NB * NPAD + 255) / 256), dim3(256), 0, stream,
                     colsq, avec, bvec, ot);
  hipLaunchKernelGGL(k_permA, dim3(NB * NC), dim3(256), 0, stream, A, fa32);
  hipLaunchKernelGGL(k_t2, dim3(MROW / 64, NC / 64, NB), dim3(256), 0, stream, fa32, fa_mh);
  hipLaunchKernelGGL(k_t2, dim3(MROW / 64, NC / 64, NB), dim3(256), 0, stream, Bf, fb_nh);

  hipLaunchKernelGGL(k_gemm, dim3(13, 13, NB), dim3(256), 0, stream,
                     fa_mh, fb_nh, colsq, corr);
  hipLaunchKernelGGL(k_normexp, dim3((NB * HW * 200 + 255) / 256), dim3(256), 0, stream,
                     corr, colsq, khat);
  hipLaunchKernelGGL(k_fill, dim3((NB * NP1 + 255) / 256), dim3(256), 0, stream,
                     khat, alpha);
  hipLaunchKernelGGL(k_tr, dim3(26, 26, NB), dim3(256), 0, stream, khat, khatT);

  dim3 sg((NB * NP1 + 3) / 4);
  for (int it = 0; it < ITERS; ++it) {
    hipLaunchKernelGGL(k_sink, sg, dim3(256), 0, stream, khat,  bvec, avec);
    hipLaunchKernelGGL(k_sink, sg, dim3(256), 0, stream, khatT, avec, bvec);
  }

  hipLaunchKernelGGL(k_ot, dim3((NB * HW + 3) / 4), dim3(256), 0, stream,
                     khat, avec, bvec, ot);
  hipLaunchKernelGGL(k_final, dim3(1), dim3(64), 0, stream, ot, out);
}

// Round 4
// 264.381 us; speedup vs baseline: 25.3013x; 1.9056x over previous
//
#include <hip/hip_runtime.h>
#include <hip/hip_fp16.h>

#define HW   1600
#define NP1  1601
#define NPAD 1608          // padded row length (elements), %8==0
#define NC   256
#define NB   8
#define MROW 1664          // GEMM row padding (13*128)
#define MU_  (1.0f/3200.0f)
#define ITERS 8            // contraction ~0.24/iter -> ~1e-5 log-residual << fp16 K noise

typedef _Float16 half8 __attribute__((ext_vector_type(8)));
typedef float    floatx4 __attribute__((ext_vector_type(4)));

// ---------- permute A planes: fa32[b][c][m] = A[b][c][m%40][m/40] ----------
__global__ void k_permA(const float* __restrict__ A, float* __restrict__ fa32) {
  __shared__ float lds[HW];
  int plane = blockIdx.x;
  const float* src = A + (size_t)plane * HW;
  float* dst = fa32 + (size_t)plane * HW;
  for (int p = threadIdx.x; p < HW; p += 256) lds[p] = src[p];
  __syncthreads();
  for (int q = threadIdx.x; q < HW; q += 256) dst[q] = lds[(q % 40) * 40 + q / 40];
}

// ---------- init ----------
__global__ void k_init(float* colsq, float* bvec) {
  int idx = blockIdx.x * 256 + threadIdx.x;
  if (idx < NB * HW) colsq[idx] = 0.f;
  if (idx < NB * NPAD) {
    int j = idx % NPAD;
    bvec[idx] = (j <= HW) ? 1.0f : 0.0f;
  }
}

// ---------- tile transpose + fp32->fp16: out[b][m][c] = in[b][c][m] ----------
__global__ __launch_bounds__(256) void k_t2(const float* __restrict__ in,
                                            _Float16* __restrict__ out) {
  __shared__ float t[64][65];
  int b  = blockIdx.z;
  int c0 = blockIdx.y * 64;
  int m0 = blockIdx.x * 64;
  int tid = threadIdx.x;
  int r = tid >> 3, jc = (tid & 7) * 8;
  const float* src = in + (size_t)b * NC * HW;
#pragma unroll
  for (int p = 0; p < 2; ++p) {
    int rr = r + p * 32;
    int c = c0 + rr;
    float4 v0 = make_float4(0.f, 0.f, 0.f, 0.f), v1 = v0;
    if (m0 < HW) {
      v0 = *(const float4*)(src + (size_t)c * HW + m0 + jc);
      v1 = *(const float4*)(src + (size_t)c * HW + m0 + jc + 4);
    }
    *(float4*)&t[rr][jc] = v0;
    *(float4*)&t[rr][jc + 4] = v1;
  }
  __syncthreads();
  _Float16* dst = out + (size_t)b * MROW * NC;
#pragma unroll
  for (int p = 0; p < 2; ++p) {
    int r2 = r + p * 32;
    int m = m0 + r2;
    _Float16 hv[8];
#pragma unroll
    for (int e = 0; e < 8; ++e) hv[e] = (_Float16)t[jc + e][r2];
    *(uint4*)(dst + (size_t)m * NC + c0 + jc) = *(uint4*)hv;
  }
}

// ---------- MFMA GEMM: khat(raw fp16) = relu(fa . fb^T), colsq += x^2 ----------
__global__ __launch_bounds__(256) void k_gemm(const _Float16* __restrict__ fa,
                                              const _Float16* __restrict__ fb,
                                              float* __restrict__ colsq,
                                              __half* __restrict__ khat) {
  __shared__ _Float16 As[128][40];
  __shared__ _Float16 Bs[128][40];
  __shared__ float cs[128];

  int b  = blockIdx.z;
  int m0 = blockIdx.y * 128;
  int n0 = blockIdx.x * 128;
  int tid = threadIdx.x, lane = tid & 63, w = tid >> 6;
  int wr = w >> 1, wc = w & 1;
  const _Float16* Ab = fa + (size_t)b * MROW * NC;
  const _Float16* Bb = fb + (size_t)b * MROW * NC;

  floatx4 acc[4][4];
#pragma unroll
  for (int i = 0; i < 4; ++i)
#pragma unroll
    for (int j = 0; j < 4; ++j) acc[i][j] = (floatx4){0.f, 0.f, 0.f, 0.f};

  for (int k0 = 0; k0 < NC; k0 += 32) {
#pragma unroll
    for (int l = 0; l < 2; ++l) {
      int id = tid + l * 256;
      int row = id >> 2, ch = id & 3;
      *(uint4*)&As[row][ch * 8] = *(const uint4*)(Ab + (size_t)(m0 + row) * NC + k0 + ch * 8);
      *(uint4*)&Bs[row][ch * 8] = *(const uint4*)(Bb + (size_t)(n0 + row) * NC + k0 + ch * 8);
    }
    __syncthreads();
    half8 af[4], bf[4];
#pragma unroll
    for (int i = 0; i < 4; ++i)
      af[i] = *(half8*)&As[wr * 64 + i * 16 + (lane & 15)][(lane >> 4) * 8];
#pragma unroll
    for (int j = 0; j < 4; ++j)
      bf[j] = *(half8*)&Bs[wc * 64 + j * 16 + (lane & 15)][(lane >> 4) * 8];
#pragma unroll
    for (int i = 0; i < 4; ++i)
#pragma unroll
      for (int j = 0; j < 4; ++j)
        acc[i][j] = __builtin_amdgcn_mfma_f32_16x16x32_f16(af[i], bf[j], acc[i][j], 0, 0, 0);
    __syncthreads();
  }

  if (tid < 128) cs[tid] = 0.f;
  __syncthreads();

#pragma unroll
  for (int j = 0; j < 4; ++j) {
    int n = n0 + wc * 64 + j * 16 + (lane & 15);
    float s = 0.f;
#pragma unroll
    for (int i = 0; i < 4; ++i) {
      int mb = m0 + wr * 64 + i * 16 + (lane >> 4) * 4;
#pragma unroll
      for (int e = 0; e < 4; ++e) {
        float x = fmaxf(acc[i][j][e], 0.f);
        s += x * x;
        int m = mb + e;
        if (m < HW && n < HW)
          khat[(size_t)(b * NP1 + m) * NPAD + n] = __float2half(x);
      }
    }
    s += __shfl_xor(s, 16, 64);
    s += __shfl_xor(s, 32, 64);
    if (lane < 16) atomicAdd(&cs[wc * 64 + j * 16 + lane], s);
  }
  __syncthreads();
  if (tid < 128) {
    int n = n0 + tid;
    if (n < HW) atomicAdd(&colsq[b * HW + n], cs[tid]);
  }
}

// ---------- fused normalize+exp (in place) + transposed copy ----------
// khat holds raw corr; khat <- exp(corr/(sqrt(colsq+eps)*16)), khatT <- khat^T
__global__ __launch_bounds__(256) void k_nt(const float* __restrict__ colsq,
                                            __half* __restrict__ khat,
                                            __half* __restrict__ khatT) {
  __shared__ __half t[64][72];
  int b  = blockIdx.z;
  int n0 = blockIdx.y * 64;       // col tile (25)
  int m0 = blockIdx.x * 64;       // row tile (25)
  int tid = threadIdx.x;
  int r = tid >> 3, jc = (tid & 7) * 8;

  float4 q0 = *(const float4*)(colsq + (size_t)b * HW + n0 + jc);
  float4 q1 = *(const float4*)(colsq + (size_t)b * HW + n0 + jc + 4);
  float qq[8] = {q0.x, q0.y, q0.z, q0.w, q1.x, q1.y, q1.z, q1.w};
  float inv[8];
#pragma unroll
  for (int e = 0; e < 8; ++e) inv[e] = 1.0f / (sqrtf(qq[e] + 1e-6f) * 16.0f);

#pragma unroll
  for (int p = 0; p < 2; ++p) {
    int rr = r + p * 32;
    int m = m0 + rr;
    __half* rp = khat + (size_t)(b * NP1 + m) * NPAD + n0 + jc;
    uint4 kk = *(const uint4*)rp;
    __half2 h0 = *(__half2*)&kk.x, h1 = *(__half2*)&kk.y;
    __half2 h2 = *(__half2*)&kk.z, h3 = *(__half2*)&kk.w;
    float x[8] = {__low2float(h0), __high2float(h0), __low2float(h1), __high2float(h1),
                  __low2float(h2), __high2float(h2), __low2float(h3), __high2float(h3)};
    __half hv[8];
#pragma unroll
    for (int e = 0; e < 8; ++e) hv[e] = __float2half(__expf(x[e] * inv[e]));
    *(uint4*)rp = *(uint4*)hv;                 // in-place elementwise
    *(uint4*)&t[rr][jc] = *(uint4*)hv;         // stage for transpose
  }
  __syncthreads();
#pragma unroll
  for (int p = 0; p < 2; ++p) {
    int r2 = r + p * 32;
    int n = n0 + r2;
    __half hv[8];
#pragma unroll
    for (int e = 0; e < 8; ++e) hv[e] = t[jc + e][r2];
    *(uint4*)(khatT + (size_t)(b * NP1 + n) * NPAD + m0 + jc) = *(uint4*)hv;
  }
}

// ---------- bin row/col fill on BOTH matrices ----------
__global__ void k_fill(__half* khat, __half* khatT, const float* alpha) {
  float E = expf(alpha[0]);
  __half he = __float2half(E);
  __half hz = __float2half(0.f);
  int idx = blockIdx.x * 256 + threadIdx.x;
  if (idx >= 2 * NB * NP1) return;
  __half* M = (idx < NB * NP1) ? khat : khatT;
  int t = idx % (NB * NP1);
  int i = t % NP1;
  __half* row = M + (size_t)t * NPAD;
  if (i < HW) {
    __half hv[8] = {he, hz, hz, hz, hz, hz, hz, hz};
    *(uint4*)(row + HW) = *(uint4*)hv;
  } else {
    for (int j = 0; j < NPAD; j += 8) {
      __half hv[8];
      for (int k = 0; k < 8; ++k) hv[k] = ((j + k) <= HW) ? he : hz;
      *(uint4*)(row + j) = *(uint4*)hv;
    }
  }
}

// ---------- Sinkhorn half-iteration: vout = mu / (K vin), wave per row ----------
__global__ __launch_bounds__(256) void k_sink(const __half* __restrict__ K,
                                              const float* __restrict__ vin,
                                              float* __restrict__ vout) {
  int wid = threadIdx.x >> 6;
  int lane = threadIdx.x & 63;
  int row = blockIdx.x * 4 + wid;
  if (row >= NB * NP1) return;
  int b = row / NP1, i = row % NP1;
  const __half* kr = K + (size_t)row * NPAD;
  const float* v = vin + (size_t)b * NPAD;
  float acc = 0.f;
  for (int c = lane; c < NPAD / 8; c += 64) {
    uint4 kk = *(const uint4*)(kr + c * 8);
    float4 v0 = *(const float4*)(v + c * 8);
    float4 v1 = *(const float4*)(v + c * 8 + 4);
    __half2 h0 = *(__half2*)&kk.x, h1 = *(__half2*)&kk.y;
    __half2 h2 = *(__half2*)&kk.z, h3 = *(__half2*)&kk.w;
    acc = fmaf(__low2float(h0),  v0.x, acc);
    acc = fmaf(__high2float(h0), v0.y, acc);
    acc = fmaf(__low2float(h1),  v0.z, acc);
    acc = fmaf(__high2float(h1), v0.w, acc);
    acc = fmaf(__low2float(h2),  v1.x, acc);
    acc = fmaf(__high2float(h2), v1.y, acc);
    acc = fmaf(__low2float(h3),  v1.z, acc);
    acc = fmaf(__high2float(h3), v1.w, acc);
  }
#pragma unroll
  for (int o = 32; o > 0; o >>= 1) acc += __shfl_xor(acc, o, 64);
  float mu = (i < HW) ? MU_ : 0.5f;
  if (lane == 0) vout[(size_t)b * NPAD + i] = mu / acc;
}

// ---------- Epilogue: wavesum[row] = a_i * sum_{j<1600} K ln(K) b_j ----------
__global__ __launch_bounds__(256) void k_ot(const __half* __restrict__ khat,
                                            const float* __restrict__ avec,
                                            const float* __restrict__ bvec,
                                            float* __restrict__ wavesum) {
  int wid = threadIdx.x >> 6;
  int lane = threadIdx.x & 63;
  int row = blockIdx.x * 4 + wid;
  if (row >= NB * HW) return;
  int b = row / HW, i = row % HW;
  const __half* kr = khat + (size_t)(b * NP1 + i) * NPAD;
  const float* bv = bvec + (size_t)b * NPAD;
  float acc = 0.f;
  for (int c = lane; c < HW / 8; c += 64) {
    uint4 kk = *(const uint4*)(kr + c * 8);
    float4 v0 = *(const float4*)(bv + c * 8);
    float4 v1 = *(const float4*)(bv + c * 8 + 4);
    __half2 h0 = *(__half2*)&kk.x, h1 = *(__half2*)&kk.y;
    __half2 h2 = *(__half2*)&kk.z, h3 = *(__half2*)&kk.w;
    float f;
    f = __low2float(h0);  acc = fmaf(f * __logf(f), v0.x, acc);
    f = __high2float(h0); acc = fmaf(f * __logf(f), v0.y, acc);
    f = __low2float(h1);  acc = fmaf(f * __logf(f), v0.z, acc);
    f = __high2float(h1); acc = fmaf(f * __logf(f), v0.w, acc);
    f = __low2float(h2);  acc = fmaf(f * __logf(f), v1.x, acc);
    f = __high2float(h2); acc = fmaf(f * __logf(f), v1.y, acc);
    f = __low2float(h3);  acc = fmaf(f * __logf(f), v1.z, acc);
    f = __high2float(h3); acc = fmaf(f * __logf(f), v1.w, acc);
  }
#pragma unroll
  for (int o = 32; o > 0; o >>= 1) acc += __shfl_xor(acc, o, 64);
  if (lane == 0) wavesum[row] = acc * avec[(size_t)b * NPAD + i];
}

// ---------- final: out[b] = exp(-3200 * sum_i wavesum[b][i]) ----------
__global__ __launch_bounds__(256) void k_final(const float* __restrict__ wavesum,
                                               float* __restrict__ out) {
  __shared__ float p[4];
  int b = blockIdx.x, tid = threadIdx.x, wid = tid >> 6, lane = tid & 63;
  float s = 0.f;
  for (int t = tid; t < HW; t += 256) s += wavesum[(size_t)b * HW + t];
#pragma unroll
  for (int o = 32; o > 0; o >>= 1) s += __shfl_xor(s, o, 64);
  if (lane == 0) p[wid] = s;
  __syncthreads();
  if (tid == 0) out[b] = expf(-3200.0f * (p[0] + p[1] + p[2] + p[3]));
}

extern "C" void kernel_launch(void* const* d_in, const int* in_sizes, int n_in,
                              void* d_out, int out_size, void* d_ws, size_t ws_size,
                              hipStream_t stream) {
  const float* A     = (const float*)d_in[0];
  const float* Bf    = (const float*)d_in[1];
  const float* alpha = (const float*)d_in[2];
  float* out = (float*)d_out;

  char* ws = (char*)d_ws;
  size_t off = 0;
  auto alloc = [&](size_t bytes) -> void* {
    void* p = (void*)(ws + off);
    off += (bytes + 255) & ~(size_t)255;
    return p;
  };
  float*    fa32   = (float*)alloc((size_t)NB * NC * HW * 4);        // 13.1 MB (reused: fb_nh)
  _Float16* fa_mh  = (_Float16*)alloc((size_t)NB * MROW * NC * 2);   // 6.8 MB
  __half*   khat   = (__half*)alloc((size_t)NB * NP1 * NPAD * 2);    // 41.2 MB (corr -> khat)
  __half*   khatT  = (__half*)alloc((size_t)NB * NP1 * NPAD * 2);    // 41.2 MB
  float*    colsq  = (float*)alloc((size_t)NB * HW * 4);
  float*    avec   = (float*)alloc((size_t)NB * NPAD * 4);
  float*    bvec   = (float*)alloc((size_t)NB * NPAD * 4);
  float*    wavesum= (float*)alloc((size_t)NB * HW * 4);

  _Float16* fb_nh = (_Float16*)fa32;   // alias: fa32 dead after k_t2(A)

  hipLaunchKernelGGL(k_init, dim3((NB * NPAD + 255) / 256), dim3(256), 0, stream,
                     colsq, bvec);
  hipLaunchKernelGGL(k_permA, dim3(NB * NC), dim3(256), 0, stream, A, fa32);
  hipLaunchKernelGGL(k_t2, dim3(MROW / 64, NC / 64, NB), dim3(256), 0, stream, fa32, fa_mh);
  hipLaunchKernelGGL(k_t2, dim3(MROW / 64, NC / 64, NB), dim3(256), 0, stream, Bf, fb_nh);

  hipLaunchKernelGGL(k_gemm, dim3(13, 13, NB), dim3(256), 0, stream,
                     fa_mh, fb_nh, colsq, khat);
  hipLaunchKernelGGL(k_nt, dim3(25, 25, NB), dim3(256), 0, stream, colsq, khat, khatT);
  hipLaunchKernelGGL(k_fill, dim3((2 * NB * NP1 + 255) / 256), dim3(256), 0, stream,
                     khat, khatT, alpha);

  dim3 sg((NB * NP1 + 3) / 4);
  for (int it = 0; it < ITERS; ++it) {
    hipLaunchKernelGGL(k_sink, sg, dim3(256), 0, stream, khat,  bvec, avec);
    hipLaunchKernelGGL(k_sink, sg, dim3(256), 0, stream, khatT, avec, bvec);
  }

  hipLaunchKernelGGL(k_ot, dim3((NB * HW + 3) / 4), dim3(256), 0, stream,
                     khat, avec, bvec, wavesum);
  hipLaunchKernelGGL(k_final, dim3(NB), dim3(256), 0, stream, wavesum, out);
}

// Round 5
// 203.590 us; speedup vs baseline: 32.8562x; 1.2986x over previous
//
#include <hip/hip_runtime.h>
#include <hip/hip_fp16.h>

#define HW    1600
#define NP1   1601
#define NPAD  1632         // row stride (halves); 3264B = 51*64 -> rows 64B-aligned
#define NCH   204          // NPAD/8
#define NC    256
#define NB    8
#define MROW  1664         // GEMM row padding (13*128)
#define MU_   (1.0f/3200.0f)
#define ITERS 6            // Birkhoff contraction ~0.214/iter -> ~1e-4 log-residual << fp16 floor

typedef _Float16 half8 __attribute__((ext_vector_type(8)));
typedef float    floatx4 __attribute__((ext_vector_type(4)));

// ---------- init: colsq=0, bvec=1(interior+bin)/0(pads), avec=0, fa/fb tails=0 ----
__global__ void k_init(float* colsq, float* avec, float* bvec,
                       _Float16* fa, _Float16* fb) {
  int idx = blockIdx.x * 256 + threadIdx.x;
  if (idx < NB * NPAD) {
    int j = idx % NPAD;
    bvec[idx] = (j <= HW) ? 1.0f : 0.0f;
    avec[idx] = 0.0f;
  }
  if (idx < NB * HW) colsq[idx] = 0.f;
  if (idx < 32768) {                       // zero rows 1600..1663 of fa_mh & fb_nh
    _Float16* dst = (idx < 16384) ? fa : fb;
    int rem = idx & 16383;
    int b = rem >> 11, q = rem & 2047;
    uint4 z = make_uint4(0, 0, 0, 0);
    *(uint4*)(dst + (size_t)b * MROW * NC + (size_t)HW * NC + q * 8) = z;
  }
}

// ---------- tile transpose + fp32->fp16 (PERM folds A's w-major flattening) ----
// out[b][m][c] = in[b][c][ PERM ? perm(m) : m ],  perm(m)=(m%40)*40+m/40 (involution)
template<bool PERM>
__global__ __launch_bounds__(256) void k_t2(const float* __restrict__ in,
                                            _Float16* __restrict__ out) {
  __shared__ float t[64][65];
  int b  = blockIdx.z;
  int c0 = blockIdx.y * 64;          // 4 tiles over NC
  int mp0 = blockIdx.x * 64;         // 25 tiles over 1600 (source index m')
  int tid = threadIdx.x;
  int r = tid >> 3, jc = (tid & 7) * 8;
  const float* src = in + (size_t)b * NC * HW;
#pragma unroll
  for (int p = 0; p < 2; ++p) {
    int rr = r + p * 32;
    int c = c0 + rr;
    *(float4*)&t[rr][jc]     = *(const float4*)(src + (size_t)c * HW + mp0 + jc);
    *(float4*)&t[rr][jc + 4] = *(const float4*)(src + (size_t)c * HW + mp0 + jc + 4);
  }
  __syncthreads();
  _Float16* dst = out + (size_t)b * MROW * NC;
#pragma unroll
  for (int p = 0; p < 2; ++p) {
    int r2 = r + p * 32;
    int mp = mp0 + r2;
    int m = PERM ? ((mp % 40) * 40 + mp / 40) : mp;   // dest row (involution)
    _Float16 hv[8];
#pragma unroll
    for (int e = 0; e < 8; ++e) hv[e] = (_Float16)t[jc + e][r2];
    *(uint4*)(dst + (size_t)m * NC + c0 + jc) = *(uint4*)hv;
  }
}

// ---------- MFMA GEMM: khat(raw fp16) = relu(fa . fb^T), colsq += x^2 ----------
// 1-D grid 1352: b = bid&7 (batch==XCD), n fastest within batch for A-panel L2 reuse.
__global__ __launch_bounds__(256) void k_gemm(const _Float16* __restrict__ fa,
                                              const _Float16* __restrict__ fb,
                                              float* __restrict__ colsq,
                                              __half* __restrict__ khat) {
  __shared__ _Float16 shmem[128 * 40 * 2];   // As | Bs, reused as stage[64][136]
  __shared__ float cs[128];
#define AS_(r, c) shmem[(r) * 40 + (c)]
#define BS_(r, c) shmem[5120 + (r) * 40 + (c)]

  int bid = blockIdx.x;
  int bb = bid & 7;
  int t  = bid >> 3;                 // 0..168
  int m0 = (t / 13) * 128;
  int n0 = (t % 13) * 128;
  int tid = threadIdx.x, lane = tid & 63, w = tid >> 6;
  int wr = w >> 1, wc = w & 1;
  const _Float16* Ab = fa + (size_t)bb * MROW * NC;
  const _Float16* Bb = fb + (size_t)bb * MROW * NC;

  floatx4 acc[4][4];
#pragma unroll
  for (int i = 0; i < 4; ++i)
#pragma unroll
    for (int j = 0; j < 4; ++j) acc[i][j] = (floatx4){0.f, 0.f, 0.f, 0.f};

  for (int k0 = 0; k0 < NC; k0 += 32) {
#pragma unroll
    for (int l = 0; l < 2; ++l) {
      int id = tid + l * 256;
      int row = id >> 2, ch = id & 3;
      *(uint4*)&AS_(row, ch * 8) = *(const uint4*)(Ab + (size_t)(m0 + row) * NC + k0 + ch * 8);
      *(uint4*)&BS_(row, ch * 8) = *(const uint4*)(Bb + (size_t)(n0 + row) * NC + k0 + ch * 8);
    }
    __syncthreads();
    half8 af[4], bf[4];
#pragma unroll
    for (int i = 0; i < 4; ++i)
      af[i] = *(half8*)&AS_(wr * 64 + i * 16 + (lane & 15), (lane >> 4) * 8);
#pragma unroll
    for (int j = 0; j < 4; ++j)
      bf[j] = *(half8*)&BS_(wc * 64 + j * 16 + (lane & 15), (lane >> 4) * 8);
#pragma unroll
    for (int i = 0; i < 4; ++i)
#pragma unroll
      for (int j = 0; j < 4; ++j)
        acc[i][j] = __builtin_amdgcn_mfma_f32_16x16x32_f16(af[i], bf[j], acc[i][j], 0, 0, 0);
    __syncthreads();
  }

  // relu in place + column sums
  if (tid < 128) cs[tid] = 0.f;
  __syncthreads();
#pragma unroll
  for (int j = 0; j < 4; ++j) {
    float s = 0.f;
#pragma unroll
    for (int i = 0; i < 4; ++i)
#pragma unroll
      for (int e = 0; e < 4; ++e) {
        float x = fmaxf(acc[i][j][e], 0.f);
        acc[i][j][e] = x;
        s += x * x;
      }
    s += __shfl_xor(s, 16, 64);
    s += __shfl_xor(s, 32, 64);
    if (lane < 16) atomicAdd(&cs[wc * 64 + j * 16 + lane], s);
  }
  __syncthreads();
  if (tid < 128) {
    int n = n0 + tid;
    if (n < HW) atomicAdd(&colsq[bb * HW + n], cs[tid]);
  }

  // LDS-staged full-line output (kills RFO partial-line writes)
  _Float16 (*stage)[136] = (_Float16(*)[136])shmem;
#pragma unroll
  for (int h = 0; h < 2; ++h) {
    __syncthreads();
    if (wr == h) {
#pragma unroll
      for (int i = 0; i < 4; ++i)
#pragma unroll
        for (int j = 0; j < 4; ++j)
#pragma unroll
          for (int e = 0; e < 4; ++e)
            stage[i * 16 + (lane >> 4) * 4 + e][wc * 64 + j * 16 + (lane & 15)] =
                (_Float16)acc[i][j][e];
    }
    __syncthreads();
    int r = tid >> 2, g = tid & 3;
    int m = m0 + h * 64 + r;
    if (m < HW) {
      __half* rowp = khat + (size_t)(bb * NP1 + m) * NPAD;
#pragma unroll
      for (int q = 0; q < 4; ++q) {
        int n = n0 + g * 32 + q * 8;
        if (n < HW)
          *(uint4*)(rowp + n) = *(uint4*)&stage[r][g * 32 + q * 8];
      }
    }
  }
}

// ---------- fused normalize+exp (in place) + transposed copy ----------
__global__ __launch_bounds__(256) void k_nt(const float* __restrict__ colsq,
                                            __half* __restrict__ khat,
                                            __half* __restrict__ khatT) {
  __shared__ __half t[64][72];
  int b  = blockIdx.z;
  int n0 = blockIdx.y * 64;
  int m0 = blockIdx.x * 64;
  int tid = threadIdx.x;
  int r = tid >> 3, jc = (tid & 7) * 8;

  float4 q0 = *(const float4*)(colsq + (size_t)b * HW + n0 + jc);
  float4 q1 = *(const float4*)(colsq + (size_t)b * HW + n0 + jc + 4);
  float qq[8] = {q0.x, q0.y, q0.z, q0.w, q1.x, q1.y, q1.z, q1.w};
  float inv[8];
#pragma unroll
  for (int e = 0; e < 8; ++e) inv[e] = 1.0f / (sqrtf(qq[e] + 1e-6f) * 16.0f);

#pragma unroll
  for (int p = 0; p < 2; ++p) {
    int rr = r + p * 32;
    int m = m0 + rr;
    __half* rp = khat + (size_t)(b * NP1 + m) * NPAD + n0 + jc;
    uint4 kk = *(const uint4*)rp;
    __half2 h0 = *(__half2*)&kk.x, h1 = *(__half2*)&kk.y;
    __half2 h2 = *(__half2*)&kk.z, h3 = *(__half2*)&kk.w;
    float x[8] = {__low2float(h0), __high2float(h0), __low2float(h1), __high2float(h1),
                  __low2float(h2), __high2float(h2), __low2float(h3), __high2float(h3)};
    __half hv[8];
#pragma unroll
    for (int e = 0; e < 8; ++e) hv[e] = __float2half(__expf(x[e] * inv[e]));
    *(uint4*)rp = *(uint4*)hv;
    *(uint4*)&t[rr][jc] = *(uint4*)hv;
  }
  __syncthreads();
#pragma unroll
  for (int p = 0; p < 2; ++p) {
    int r2 = r + p * 32;
    int n = n0 + r2;
    __half hv[8];
#pragma unroll
    for (int e = 0; e < 8; ++e) hv[e] = t[jc + e][r2];
    *(uint4*)(khatT + (size_t)(b * NP1 + n) * NPAD + m0 + jc) = *(uint4*)hv;
  }
}

// ---------- bin row + pad-col fill on BOTH matrices ----------
__global__ void k_fill(__half* khat, __half* khatT, const float* alpha) {
  float E = expf(alpha[0]);
  __half he = __float2half(E);
  __half hz = __float2half(0.f);
  int idx = blockIdx.x * 256 + threadIdx.x;
  if (idx >= 2 * NB * NP1) return;
  __half* M = (idx < NB * NP1) ? khat : khatT;
  int t = idx % (NB * NP1);
  int i = t % NP1;
  __half* row = M + (size_t)t * NPAD;
  if (i < HW) {                       // interior row: cols 1600..1631 = {E,0,...,0}
    __half hv[8] = {he, hz, hz, hz, hz, hz, hz, hz};
    *(uint4*)(row + HW) = *(uint4*)hv;
    uint4 z = make_uint4(0, 0, 0, 0);
    *(uint4*)(row + HW + 8)  = z;
    *(uint4*)(row + HW + 16) = z;
    *(uint4*)(row + HW + 24) = z;
  } else {                            // bin row: E everywhere incl corner, pads 0
    for (int j = 0; j < NPAD; j += 8) {
      __half hv[8];
      for (int k = 0; k < 8; ++k) hv[k] = ((j + k) <= HW) ? he : hz;
      *(uint4*)(row + j) = *(uint4*)hv;
    }
  }
}

// ---------- Sinkhorn half-step, 2 rows/wave (shared v loads) ----------
// wave handles rows (b, t) and (b, t+801), t in 0..800; (b,1601) is a dummy.
__global__ __launch_bounds__(256) void k_sink2(const __half* __restrict__ K,
                                               const float* __restrict__ vin,
                                               float* __restrict__ vout) {
  int wid = threadIdx.x >> 6, lane = threadIdx.x & 63;
  int pair = blockIdx.x * 4 + wid;                 // 0..6407
  int b = pair / 801, t = pair % 801;
  int i0 = t, i1 = t + 801;
  bool has1 = (i1 <= HW);
  const __half* k0 = K + ((size_t)b * NP1 + i0) * NPAD;
  const __half* k1 = has1 ? K + ((size_t)b * NP1 + i1) * NPAD : k0;
  const float* v = vin + (size_t)b * NPAD;
  float a0 = 0.f, a1 = 0.f;
  for (int c = lane; c < NCH; c += 64) {
    uint4 ka = *(const uint4*)(k0 + c * 8);
    uint4 kb = *(const uint4*)(k1 + c * 8);
    float4 v0 = *(const float4*)(v + c * 8);
    float4 v1 = *(const float4*)(v + c * 8 + 4);
    __half2 p0 = *(__half2*)&ka.x, p1 = *(__half2*)&ka.y;
    __half2 p2 = *(__half2*)&ka.z, p3 = *(__half2*)&ka.w;
    __half2 q0 = *(__half2*)&kb.x, q1 = *(__half2*)&kb.y;
    __half2 q2 = *(__half2*)&kb.z, q3 = *(__half2*)&kb.w;
    a0 = fmaf(__low2float(p0),  v0.x, a0);  a1 = fmaf(__low2float(q0),  v0.x, a1);
    a0 = fmaf(__high2float(p0), v0.y, a0);  a1 = fmaf(__high2float(q0), v0.y, a1);
    a0 = fmaf(__low2float(p1),  v0.z, a0);  a1 = fmaf(__low2float(q1),  v0.z, a1);
    a0 = fmaf(__high2float(p1), v0.w, a0);  a1 = fmaf(__high2float(q1), v0.w, a1);
    a0 = fmaf(__low2float(p2),  v1.x, a0);  a1 = fmaf(__low2float(q2),  v1.x, a1);
    a0 = fmaf(__high2float(p2), v1.y, a0);  a1 = fmaf(__high2float(q2), v1.y, a1);
    a0 = fmaf(__low2float(p3),  v1.z, a0);  a1 = fmaf(__low2float(q3),  v1.z, a1);
    a0 = fmaf(__high2float(p3), v1.w, a0);  a1 = fmaf(__high2float(q3), v1.w, a1);
  }
#pragma unroll
  for (int o = 32; o > 0; o >>= 1) { a0 += __shfl_xor(a0, o, 64); a1 += __shfl_xor(a1, o, 64); }
  if (lane == 0) {
    vout[(size_t)b * NPAD + i0] = MU_ / a0;
    if (has1) vout[(size_t)b * NPAD + i1] = ((i1 == HW) ? 0.5f : MU_) / a1;
  }
}

// ---------- final b-half-step fused with OT epilogue (scans khatT) ----------
// row j: acc = sum_i K[i][j] a_i (all i);  acc2 = sum_{i<HW} K lnK a_i
// wavesum[b][j] = (MU_/acc) * acc2
__global__ __launch_bounds__(256) void k_sink_ot(const __half* __restrict__ KT,
                                                 const float* __restrict__ avec,
                                                 float* __restrict__ wavesum) {
  int wid = threadIdx.x >> 6, lane = threadIdx.x & 63;
  int row = blockIdx.x * 4 + wid;
  if (row >= NB * HW) return;
  int b = row / HW, j = row % HW;
  const __half* kr = KT + ((size_t)b * NP1 + j) * NPAD;
  const float* v = avec + (size_t)b * NPAD;
  float acc = 0.f, acc2 = 0.f;
  for (int c = lane; c < NCH; c += 64) {
    uint4 kk = *(const uint4*)(kr + c * 8);
    float4 v0 = *(const float4*)(v + c * 8);
    float4 v1 = *(const float4*)(v + c * 8 + 4);
    __half2 h0 = *(__half2*)&kk.x, h1 = *(__half2*)&kk.y;
    __half2 h2 = *(__half2*)&kk.z, h3 = *(__half2*)&kk.w;
    float f0 = __low2float(h0), f1 = __high2float(h0);
    float f2 = __low2float(h1), f3 = __high2float(h1);
    float f4 = __low2float(h2), f5 = __high2float(h2);
    float f6 = __low2float(h3), f7 = __high2float(h3);
    acc = fmaf(f0, v0.x, acc); acc = fmaf(f1, v0.y, acc);
    acc = fmaf(f2, v0.z, acc); acc = fmaf(f3, v0.w, acc);
    acc = fmaf(f4, v1.x, acc); acc = fmaf(f5, v1.y, acc);
    acc = fmaf(f6, v1.z, acc); acc = fmaf(f7, v1.w, acc);
    if (c < HW / 8) {                    // interior i only for the OT sum
      acc2 = fmaf(f0 * __logf(f0), v0.x, acc2);
      acc2 = fmaf(f1 * __logf(f1), v0.y, acc2);
      acc2 = fmaf(f2 * __logf(f2), v0.z, acc2);
      acc2 = fmaf(f3 * __logf(f3), v0.w, acc2);
      acc2 = fmaf(f4 * __logf(f4), v1.x, acc2);
      acc2 = fmaf(f5 * __logf(f5), v1.y, acc2);
      acc2 = fmaf(f6 * __logf(f6), v1.z, acc2);
      acc2 = fmaf(f7 * __logf(f7), v1.w, acc2);
    }
  }
#pragma unroll
  for (int o = 32; o > 0; o >>= 1) { acc += __shfl_xor(acc, o, 64); acc2 += __shfl_xor(acc2, o, 64); }
  if (lane == 0) wavesum[row] = (MU_ / acc) * acc2;
}

// ---------- final: out[b] = exp(-3200 * sum_j wavesum[b][j]) ----------
__global__ __launch_bounds__(256) void k_final(const float* __restrict__ wavesum,
                                               float* __restrict__ out) {
  __shared__ float p[4];
  int b = blockIdx.x, tid = threadIdx.x, wid = tid >> 6, lane = tid & 63;
  float s = 0.f;
  for (int t = tid; t < HW; t += 256) s += wavesum[(size_t)b * HW + t];
#pragma unroll
  for (int o = 32; o > 0; o >>= 1) s += __shfl_xor(s, o, 64);
  if (lane == 0) p[wid] = s;
  __syncthreads();
  if (tid == 0) out[b] = expf(-3200.0f * (p[0] + p[1] + p[2] + p[3]));
}

extern "C" void kernel_launch(void* const* d_in, const int* in_sizes, int n_in,
                              void* d_out, int out_size, void* d_ws, size_t ws_size,
                              hipStream_t stream) {
  const float* A     = (const float*)d_in[0];
  const float* Bf    = (const float*)d_in[1];
  const float* alpha = (const float*)d_in[2];
  float* out = (float*)d_out;

  char* ws = (char*)d_ws;
  size_t off = 0;
  auto alloc = [&](size_t bytes) -> void* {
    void* p = (void*)(ws + off);
    off += (bytes + 255) & ~(size_t)255;
    return p;
  };
  _Float16* fa_mh  = (_Float16*)alloc((size_t)NB * MROW * NC * 2);   // 6.8 MB
  _Float16* fb_nh  = (_Float16*)alloc((size_t)NB * MROW * NC * 2);   // 6.8 MB
  __half*   khat   = (__half*)alloc((size_t)NB * NP1 * NPAD * 2);    // 41.8 MB
  __half*   khatT  = (__half*)alloc((size_t)NB * NP1 * NPAD * 2);    // 41.8 MB
  float*    colsq  = (float*)alloc((size_t)NB * HW * 4);
  float*    avec   = (float*)alloc((size_t)NB * NPAD * 4);
  float*    bvec   = (float*)alloc((size_t)NB * NPAD * 4);
  float*    wavesum= (float*)alloc((size_t)NB * HW * 4);

  hipLaunchKernelGGL(k_init, dim3(128), dim3(256), 0, stream,
                     colsq, avec, bvec, fa_mh, fb_nh);
  hipLaunchKernelGGL((k_t2<true>),  dim3(25, 4, NB), dim3(256), 0, stream, A,  fa_mh);
  hipLaunchKernelGGL((k_t2<false>), dim3(25, 4, NB), dim3(256), 0, stream, Bf, fb_nh);

  hipLaunchKernelGGL(k_gemm, dim3(1352), dim3(256), 0, stream,
                     fa_mh, fb_nh, colsq, khat);
  hipLaunchKernelGGL(k_nt, dim3(25, 25, NB), dim3(256), 0, stream, colsq, khat, khatT);
  hipLaunchKernelGGL(k_fill, dim3((2 * NB * NP1 + 255) / 256), dim3(256), 0, stream,
                     khat, khatT, alpha);

  dim3 sg(1602);
  for (int it = 0; it < ITERS; ++it) {
    hipLaunchKernelGGL(k_sink2, sg, dim3(256), 0, stream, khat, bvec, avec);
    if (it < ITERS - 1)
      hipLaunchKernelGGL(k_sink2, sg, dim3(256), 0, stream, khatT, avec, bvec);
  }
  hipLaunchKernelGGL(k_sink_ot, dim3((NB * HW + 3) / 4), dim3(256), 0, stream,
                     khatT, avec, wavesum);
  hipLaunchKernelGGL(k_final, dim3(NB), dim3(256), 0, stream, wavesum, out);
}